// Round 9
// baseline (336.480 us; speedup 1.0000x reference)
//
#include <hip/hip_runtime.h>
#include <hip/hip_bf16.h>
#include <math.h>

// Problem constants: B,T,D = 8,2048,1024; HID=1024, OUT=512, H=4, WIN=9
#define B_    8
#define T_    2048
#define D_    1024
#define HID_  1024
#define H_    4
#define DK_   256     // HID_/H_
#define S_ELEMS ((size_t)16384 * 1024)   // M * HID

typedef __bf16 bf16x8  __attribute__((ext_vector_type(8)));
typedef __bf16 bf16x4v __attribute__((ext_vector_type(4)));
typedef float  f32x4   __attribute__((ext_vector_type(4)));

__device__ __forceinline__ float gelu_f(float x) {
    return 0.5f * x * (1.0f + erff(x * 0.70710678118654752440f));
}

__device__ __forceinline__ void gload_lds16(const void* g, void* s) {
    __builtin_amdgcn_global_load_lds(
        (const __attribute__((address_space(1))) void*)g,
        (__attribute__((address_space(3))) void*)s, 16, 0, 0);
}

// ---------------------------------------------------------------------------
// 256x256 bf16 GEMM, v4: m201-style phase discipline.
// BK=64, 8 waves (2Mx4N), 512 threads, T2 LDS swizzle (verified 0 conflicts).
// Staging (proven, never blocks): stage tile t+1 fully (8 gload_lds) at top of
// tile t; vmcnt(8) retires tile t's loads (issued one full tile earlier).
// Compute: 4 quadrant phases, reads {12,4,8,0} (B0 frags live ph1->ph4):
//   ph1: rd A[0-63](8) + B[0-31](4) | bar | lgkm0 | 16 MFMA acc[0-3][0-1] | bar
//   ph2: rd B[32-63](4)             | bar | lgkm0 | 16 MFMA acc[0-3][2-3] | bar
//   ph3: rd A[64-127](8)            | bar | lgkm0 | 16 MFMA acc[4-7][2-3] | bar
//   ph4: (no reads)                 | bar |         16 MFMA acc[4-7][0-1] | bar
// The barrier BETWEEN read-issue and MFMA-burst + explicit lgkmcnt(0) (+
// sched_barrier, rule 18) gives a clean back-to-back MFMA burst per phase
// (m196/m201: the fine interleave is the lever; compiler-interleaved waits
// inside the burst cost 7-27%).
// EPI 0: QKV fused - Cb+sel*S_ELEMS gets bf16(acc+bias[col]); sel = col>>10
// EPI 1: Cb[m,n] = bf16(acc + bias[n] + res[m,n])   (O-proj + residual, bf16)
// ---------------------------------------------------------------------------
template<int EPI>
__global__ __launch_bounds__(512) void gemm256_k(
    const __bf16* __restrict__ A, const __bf16* __restrict__ Bt,
    const float* __restrict__ bias, const float* __restrict__ res,
    float* __restrict__ Cf, __bf16* __restrict__ Cb,
    int M, int N, int K)
{
    __shared__ __bf16 lds[2][2][256 * 64];
    const int tid = threadIdx.x;
    const int w  = tid >> 6, l = tid & 63;
    const int wm = w >> 2,  wn = w & 3;
    const int lr = l & 15, lq = l >> 4, lx = l & 7;
    const int m0 = blockIdx.x * 256, n0 = blockIdx.y * 256;
    const int nt = K >> 6;

    f32x4 acc[8][4] = {};

    int srow[4], sslot[4];
    #pragma unroll
    for (int c = 0; c < 4; ++c) {
        int i = tid + c * 512;
        srow[c]  = i >> 3;
        sslot[c] = (i & 7) ^ (srow[c] & 7);
    }
    const int ldsu = (w * 64) * 16;

    auto stageA = [&](int t) {
        char* dst = (char*)&lds[t & 1][0][0];
        #pragma unroll
        for (int c = 0; c < 4; ++c)
            gload_lds16((const char*)(A + (size_t)(m0 + srow[c]) * K + t * 64) + (sslot[c] << 4),
                        dst + ldsu + c * 512 * 16);
    };
    auto stageB = [&](int t) {
        char* dst = (char*)&lds[t & 1][1][0];
        #pragma unroll
        for (int c = 0; c < 4; ++c)
            gload_lds16((const char*)(Bt + (size_t)(n0 + srow[c]) * K + t * 64) + (sslot[c] << 4),
                        dst + ldsu + c * 512 * 16);
    };

    stageA(0);
    stageB(0);

    for (int t = 0; t < nt; ++t) {
        const int cur = t & 1;
        if (t + 1 < nt) {
            stageA(t + 1);
            stageB(t + 1);
            asm volatile("s_waitcnt vmcnt(8)" ::: "memory");   // tile t resident
        } else {
            asm volatile("s_waitcnt vmcnt(0)" ::: "memory");
        }
        __builtin_amdgcn_s_barrier();
        asm volatile("" ::: "memory");

        const char* Ap = (const char*)&lds[cur][0][0];
        const char* Bp = (const char*)&lds[cur][1][0];

        bf16x8 af[2][4], b0[2][2], b1[2][2];

        auto rdA = [&](int ah) {
            #pragma unroll
            for (int ks = 0; ks < 2; ++ks)
                #pragma unroll
                for (int fi = 0; fi < 4; ++fi)
                    af[ks][fi] = *(const bf16x8*)(Ap + (wm * 128 + (ah * 64) + fi * 16 + lr) * 128
                                                     + ((((ks << 2) | lq) ^ lx) << 4));
        };
        auto rdB = [&](bf16x8 (&bb)[2][2], int bh) {
            #pragma unroll
            for (int ks = 0; ks < 2; ++ks)
                #pragma unroll
                for (int fj = 0; fj < 2; ++fj)
                    bb[ks][fj] = *(const bf16x8*)(Bp + (wn * 64 + (bh * 32) + fj * 16 + lr) * 128
                                                     + ((((ks << 2) | lq) ^ lx) << 4));
        };
        auto burst = [&](bf16x8 (&bb)[2][2], int ai, int bj) {
            __builtin_amdgcn_s_barrier();
            asm volatile("s_waitcnt lgkmcnt(0)" ::: "memory");
            __builtin_amdgcn_sched_barrier(0);
            __builtin_amdgcn_s_setprio(1);
            #pragma unroll
            for (int ks = 0; ks < 2; ++ks)
                #pragma unroll
                for (int fi = 0; fi < 4; ++fi)
                    #pragma unroll
                    for (int fj = 0; fj < 2; ++fj)
                        acc[ai + fi][bj + fj] = __builtin_amdgcn_mfma_f32_16x16x32_bf16(
                            af[ks][fi], bb[ks][fj], acc[ai + fi][bj + fj], 0, 0, 0);
            __builtin_amdgcn_s_setprio(0);
            __builtin_amdgcn_s_barrier();
            asm volatile("" ::: "memory");
        };

        rdA(0); rdB(b0, 0);
        burst(b0, 0, 0);            // ph1
        rdB(b1, 1);
        burst(b1, 0, 2);            // ph2
        rdA(1);
        burst(b1, 4, 2);            // ph3
        burst(b0, 4, 0);            // ph4 (no reads; b0 kept from ph1)
    }

    #pragma unroll
    for (int fi = 0; fi < 8; ++fi) {
        const int row0 = m0 + wm * 128 + fi * 16 + lq * 4;
        #pragma unroll
        for (int fj = 0; fj < 4; ++fj) {
            const int col = n0 + wn * 64 + fj * 16 + lr;
            const float bz = bias[col];
            if (EPI == 0) {
                const int sel = col >> 10, cl = col & 1023;
                __bf16* out = Cb + (size_t)sel * S_ELEMS + (size_t)row0 * 1024 + cl;
                #pragma unroll
                for (int r = 0; r < 4; ++r)
                    out[(size_t)r * 1024] = (__bf16)(acc[fi][fj][r] + bz);
            } else {
                #pragma unroll
                for (int r = 0; r < 4; ++r) {
                    size_t idx = (size_t)(row0 + r) * N + col;
                    Cb[idx] = (__bf16)(acc[fi][fj][r] + bz + res[idx]);
                }
            }
        }
    }
}

// ---------------------------------------------------------------------------
// m97-structure 128x128 bf16 GEMM (FFN1/FFN2)
// EPI 2: Cf[b,n,t] = gelu(acc+bias)  AND  Cb[m,n] = bf16(gelu)  (FFN1)
// EPI 3: Cf[b,n,t] = gelu(acc+bias)                             (FFN2)
// ---------------------------------------------------------------------------
template<int EPI>
__global__ __launch_bounds__(256) void mm_k(
    const __bf16* __restrict__ A, const __bf16* __restrict__ Bt,
    const float* __restrict__ bias, const float* __restrict__ res,
    float* __restrict__ Cf, __bf16* __restrict__ Cb,
    int M, int N, int K)
{
    __shared__ __bf16 As[128 * 32];
    __shared__ __bf16 Bs[128 * 32];
    const int tid = threadIdx.x;
    const int w   = tid >> 6;
    const int l   = tid & 63;
    const int wm  = w >> 1, wn = w & 1;
    const int m0  = blockIdx.x * 128, n0 = blockIdx.y * 128;
    const int lr  = l & 15;
    const int lq  = l >> 4;

    f32x4 acc[4][4] = {};

    const int ar0 = tid >> 2,          ak0 = (tid & 3) * 8;
    const int ar1 = (tid + 256) >> 2,  ak1 = (tid & 3) * 8;
    char* As_b = (char*)As;
    char* Bs_b = (char*)Bs;
    char* ldsA0 = As_b + (w * 64) * 16;
    char* ldsA1 = As_b + (w * 64 + 256) * 16;
    char* ldsB0 = Bs_b + (w * 64) * 16;
    char* ldsB1 = Bs_b + (w * 64 + 256) * 16;

    for (int k0 = 0; k0 < K; k0 += 32) {
        gload_lds16(A  + (size_t)(m0 + ar0) * K + k0 + ak0, ldsA0);
        gload_lds16(A  + (size_t)(m0 + ar1) * K + k0 + ak1, ldsA1);
        gload_lds16(Bt + (size_t)(n0 + ar0) * K + k0 + ak0, ldsB0);
        gload_lds16(Bt + (size_t)(n0 + ar1) * K + k0 + ak1, ldsB1);
        __syncthreads();

        const __bf16* Ab = As + (wm * 64 + lr) * 32 + lq * 8;
        const __bf16* Bb = Bs + (wn * 64 + lr) * 32 + lq * 8;
        bf16x8 a[4], b[4];
        #pragma unroll
        for (int i = 0; i < 4; ++i) a[i] = *(const bf16x8*)(Ab + i * 16 * 32);
        #pragma unroll
        for (int j = 0; j < 4; ++j) b[j] = *(const bf16x8*)(Bb + j * 16 * 32);
        #pragma unroll
        for (int i = 0; i < 4; ++i)
            #pragma unroll
            for (int j = 0; j < 4; ++j)
                acc[i][j] = __builtin_amdgcn_mfma_f32_16x16x32_bf16(
                    a[i], b[j], acc[i][j], 0, 0, 0);
        __syncthreads();
    }

    #pragma unroll
    for (int i = 0; i < 4; ++i) {
        const int row0 = m0 + wm * 64 + i * 16 + lq * 4;
        #pragma unroll
        for (int j = 0; j < 4; ++j) {
            const int col = n0 + wn * 64 + j * 16 + lr;
            const float bz = bias[col];
            float gv[4];
            #pragma unroll
            for (int r = 0; r < 4; ++r) gv[r] = gelu_f(acc[i][j][r] + bz);
            const int bidx = row0 >> 11, t0 = row0 & (T_ - 1);
            float4 g4; g4.x = gv[0]; g4.y = gv[1]; g4.z = gv[2]; g4.w = gv[3];
            *(float4*)(Cf + (size_t)bidx * N * T_ + (size_t)col * T_ + t0) = g4;
            if (EPI == 2) {
                #pragma unroll
                for (int r = 0; r < 4; ++r)
                    Cb[(size_t)(row0 + r) * N + col] = (__bf16)gv[r];
            }
        }
    }
}

// ---------------------------------------------------------------------------
// Windowed attention v3 (round-5 proven): 8 threads/query, 32-dim slices,
// no LDS, no barriers; 8-lane shfl reduce; per-lane softmax.
// ---------------------------------------------------------------------------
__global__ __launch_bounds__(256) void attn3_k(
    const __bf16* Q, const __bf16* __restrict__ Kg, const __bf16* __restrict__ Vg,
    __bf16* O, const float* __restrict__ aw_p, const float* __restrict__ ab_p)
{
    const int tid = threadIdx.x;
    const int g  = tid & 7;
    const int ql = tid >> 3;
    const int b  = blockIdx.x >> 8;
    const int h  = (blockIdx.x >> 6) & 3;
    const int t  = ((blockIdx.x & 63) << 5) + ql;

    const size_t hbase = (size_t)b * T_ * HID_ + h * DK_ + g * 32;

    const __bf16* qp = Q + hbase + (size_t)t * HID_;
    float qf[32];
    #pragma unroll
    for (int c = 0; c < 4; ++c) {
        bf16x8 v = *(const bf16x8*)(qp + c * 8);
        #pragma unroll
        for (int e = 0; e < 8; ++e) qf[c * 8 + e] = (float)v[e];
    }

    float part[9];
    #pragma unroll
    for (int jj = 0; jj < 9; ++jj) {
        int j  = t - 4 + jj;
        int jc = min(max(j, 0), T_ - 1);
        const __bf16* kp = Kg + hbase + (size_t)jc * HID_;
        float s = 0.f;
        #pragma unroll
        for (int c = 0; c < 4; ++c) {
            bf16x8 kv = *(const bf16x8*)(kp + c * 8);
            #pragma unroll
            for (int e = 0; e < 8; ++e) s = fmaf(qf[c * 8 + e], (float)kv[e], s);
        }
        part[jj] = s;
    }

    #pragma unroll
    for (int jj = 0; jj < 9; ++jj) {
        float v = part[jj];
        v += __shfl_xor(v, 1);
        v += __shfl_xor(v, 2);
        v += __shfl_xor(v, 4);
        part[jj] = v;
    }

    const float aw = *aw_p, ab = *ab_p;
    float sc[9], mx = -1e30f;
    #pragma unroll
    for (int jj = 0; jj < 9; ++jj) {
        int j = t - 4 + jj;
        float d = (float)(jj - 4);
        float adj = __expf(-fabsf(aw * d * d - ab));
        sc[jj] = (j >= 0 && j < T_) ? part[jj] * (1.0f / 16.0f) + adj : -1e30f;
        mx = fmaxf(mx, sc[jj]);
    }
    float wgt[9], sum = 0.f;
    #pragma unroll
    for (int jj = 0; jj < 9; ++jj) { wgt[jj] = __expf(sc[jj] - mx); sum += wgt[jj]; }
    const float inv = 1.0f / sum;

    float o[32];
    #pragma unroll
    for (int e = 0; e < 32; ++e) o[e] = 0.f;
    #pragma unroll
    for (int jj = 0; jj < 9; ++jj) {
        int jc = min(max(t - 4 + jj, 0), T_ - 1);
        const float wj = wgt[jj] * inv;
        const __bf16* vp = Vg + hbase + (size_t)jc * HID_;
        #pragma unroll
        for (int c = 0; c < 4; ++c) {
            bf16x8 vv = *(const bf16x8*)(vp + c * 8);
            #pragma unroll
            for (int e = 0; e < 8; ++e)
                o[c * 8 + e] = fmaf(wj, (float)vv[e], o[c * 8 + e]);
        }
    }

    __bf16* op = O + hbase + (size_t)t * HID_;
    #pragma unroll
    for (int c = 0; c < 4; ++c) {
        bf16x8 ov;
        #pragma unroll
        for (int e = 0; e < 8; ++e) ov[e] = (__bf16)o[c * 8 + e];
        *(bf16x8*)(op + c * 8) = ov;
    }
}

// ---------------------------------------------------------------------------
// LayerNorm over D=1024: bf16 in-place. One 256-thread block per row.
// ---------------------------------------------------------------------------
__device__ __forceinline__ float block_sum(float v, float* sm) {
    #pragma unroll
    for (int off = 32; off; off >>= 1) v += __shfl_xor(v, off);
    if ((threadIdx.x & 63) == 0) sm[threadIdx.x >> 6] = v;
    __syncthreads();
    float r = sm[0] + sm[1] + sm[2] + sm[3];
    __syncthreads();
    return r;
}

__global__ __launch_bounds__(256) void ln_k(
    __bf16* __restrict__ Yb, const float* __restrict__ g, const float* __restrict__ bta)
{
    __shared__ float sm[4];
    __bf16* y = Yb + (size_t)blockIdx.x * D_;
    bf16x4v v4 = *(const bf16x4v*)(y + threadIdx.x * 4);
    float v[4] = { (float)v4[0], (float)v4[1], (float)v4[2], (float)v4[3] };
    float mean = block_sum(v[0] + v[1] + v[2] + v[3], sm) * (1.0f / D_);
    float s2 = 0.f;
    #pragma unroll
    for (int i = 0; i < 4; ++i) { float d = v[i] - mean; s2 += d * d; }
    float rstd = rsqrtf(block_sum(s2, sm) * (1.0f / D_) + 1e-5f);
    bf16x4v o;
    #pragma unroll
    for (int i = 0; i < 4; ++i) {
        int idx = threadIdx.x * 4 + i;
        o[i] = (__bf16)((v[i] - mean) * rstd * g[idx] + bta[idx]);
    }
    *(bf16x4v*)(y + threadIdx.x * 4) = o;
}

// ---------------------------------------------------------------------------
// Fused prep: cast x (16384 blocks), W1 (512), W2 (256), pack biases (12).
// ---------------------------------------------------------------------------
__global__ __launch_bounds__(256) void prep_k(
    const float4* __restrict__ x4, const float4* __restrict__ W14,
    const float4* __restrict__ W24,
    const float* __restrict__ bq, const float* __restrict__ bk,
    const float* __restrict__ bv,
    bf16x4v* __restrict__ xb4, bf16x4v* __restrict__ W1b4,
    bf16x4v* __restrict__ W2b4, float* __restrict__ bqkvd)
{
    const int bid = blockIdx.x, tid = threadIdx.x;
    if (bid < 16384) {
        int i = bid * 256 + tid;
        float4 v = x4[i];
        bf16x4v o; o[0] = (__bf16)v.x; o[1] = (__bf16)v.y; o[2] = (__bf16)v.z; o[3] = (__bf16)v.w;
        xb4[i] = o;
    } else if (bid < 16896) {
        int i = (bid - 16384) * 256 + tid;
        float4 v = W14[i];
        bf16x4v o; o[0] = (__bf16)v.x; o[1] = (__bf16)v.y; o[2] = (__bf16)v.z; o[3] = (__bf16)v.w;
        W1b4[i] = o;
    } else if (bid < 17152) {
        int i = (bid - 16896) * 256 + tid;
        float4 v = W24[i];
        bf16x4v o; o[0] = (__bf16)v.x; o[1] = (__bf16)v.y; o[2] = (__bf16)v.z; o[3] = (__bf16)v.w;
        W2b4[i] = o;
    } else {
        int i = (bid - 17152) * 256 + tid;   // 0..3071
        bqkvd[i] = (i < 1024) ? bq[i] : ((i < 2048) ? bk[i - 1024] : bv[i - 2048]);
    }
}

// castT of the four 1024x1024 weights in one launch (blockIdx.z selects).
__global__ void castT4_k(const float* __restrict__ Wq, const float* __restrict__ Wk,
                         const float* __restrict__ Wv, const float* __restrict__ Wo,
                         __bf16* __restrict__ Wqkv, __bf16* __restrict__ Wot)
{
    __shared__ float tbuf[32][33];
    const int z = blockIdx.z;
    const float* in = (z == 0) ? Wq : (z == 1) ? Wk : (z == 2) ? Wv : Wo;
    __bf16* out = (z < 3) ? (Wqkv + (size_t)z * 1024 * 1024) : Wot;
    int k0 = blockIdx.x * 32, n0 = blockIdx.y * 32;
    for (int r = threadIdx.y; r < 32; r += 8)
        tbuf[r][threadIdx.x] = in[(size_t)(k0 + r) * 1024 + n0 + threadIdx.x];
    __syncthreads();
    for (int r = threadIdx.y; r < 32; r += 8)
        out[(size_t)(n0 + r) * 1024 + k0 + threadIdx.x] = (__bf16)tbuf[threadIdx.x][r];
}

// ---------------------------------------------------------------------------
extern "C" void kernel_launch(void* const* d_in, const int* in_sizes, int n_in,
                              void* d_out, int out_size, void* d_ws, size_t ws_size,
                              hipStream_t stream) {
    const float* x    = (const float*)d_in[0];
    const float* Wq   = (const float*)d_in[2];
    const float* bq   = (const float*)d_in[3];
    const float* Wk   = (const float*)d_in[4];
    const float* bk   = (const float*)d_in[5];
    const float* Wv   = (const float*)d_in[6];
    const float* bv   = (const float*)d_in[7];
    const float* Wo   = (const float*)d_in[8];
    const float* bo   = (const float*)d_in[9];
    const float* ln_g = (const float*)d_in[10];
    const float* ln_b = (const float*)d_in[11];
    const float* W1   = (const float*)d_in[12];  // [512,1024] already [N,K]
    const float* b1   = (const float*)d_in[13];
    const float* W2   = (const float*)d_in[14];  // [512,512]  already [N,K]
    const float* b2   = (const float*)d_in[15];
    const float* adj_w = (const float*)d_in[16];
    const float* adj_b = (const float*)d_in[17];

    const int M = B_ * T_;                  // 16384
    const size_t S = S_ELEMS;               // 16.78M elems

    __bf16* Qb   = (__bf16*)d_ws;           // S  (also attention output O)
    __bf16* Kb   = Qb + S;                  // S  (dead after attn -> Yb bf16)
    __bf16* Vb   = Kb + S;                  // S
    __bf16* Yb   = Kb;                      // alias: post-residual bf16 y
    __bf16* xb   = Vb + S;                  // S
    __bf16* Wqkv = xb + S;                  // 3*1M  ([3072,1024] bf16, N-major)
    __bf16* Wot  = Wqkv + 3 * 1024 * 1024;  // 1M
    __bf16* W1b  = Wot + 1024 * 1024;       // 512*1024
    __bf16* W2b  = W1b + 512 * 1024;        // 512*512
    __bf16* h1b  = W2b + 512 * 512;         // M*512
    float*  bqkvd = (float*)(h1b + (size_t)M * 512);  // 3072 f32

    float* xe = (float*)d_out;                         // [B,512,T]
    float* h1 = xe + (size_t)B_ * 512 * T_;            // [B,512,T]

    dim3 blk(256);

    // --- prep: casts + bias pack (2 launches) ---
    prep_k<<<dim3(17164), blk, 0, stream>>>(
        (const float4*)x, (const float4*)W1, (const float4*)W2, bq, bk, bv,
        (bf16x4v*)xb, (bf16x4v*)W1b, (bf16x4v*)W2b, bqkvd);
    castT4_k<<<dim3(32, 32, 4), dim3(32, 8), 0, stream>>>(Wq, Wk, Wv, Wo, Wqkv, Wot);

    // --- QKV fused projection (256^2 phase-discipline MFMA): N=3072 ---
    gemm256_k<0><<<dim3(M / 256, 3072 / 256), dim3(512), 0, stream>>>(
        xb, Wqkv, bqkvd, nullptr, nullptr, Qb, M, 3072, D_);

    // --- windowed attention v3 (O overwrites Qb) ---
    attn3_k<<<dim3(B_ * H_ * (T_ / 32)), blk, 0, stream>>>(Qb, Kb, Vb, Qb, adj_w, adj_b);

    // --- O-projection + bias + residual -> Yb bf16 ---
    gemm256_k<1><<<dim3(M / 256, HID_ / 256), dim3(512), 0, stream>>>(
        Qb, Wot, bo, x, nullptr, Yb, M, D_, HID_);

    // --- LayerNorm in place (bf16) ---
    ln_k<<<dim3(M), blk, 0, stream>>>(Yb, ln_g, ln_b);

    // --- FFN1: gelu(W1 @ y^T): f32 transposed to h1, bf16 row-major to h1b ---
    dim3 gF(M / 128, 512 / 128);
    mm_k<2><<<gF, blk, 0, stream>>>(Yb, W1b, b1, nullptr, h1, h1b, M, 512, D_);

    // --- FFN2: gelu(W2 @ h1): f32 transposed to xe ---
    mm_k<3><<<gF, blk, 0, stream>>>(h1b, W2b, b2, nullptr, xe, nullptr, M, 512, 512);
}

// Round 10
// 319.166 us; speedup vs baseline: 1.0543x; 1.0543x over previous
//
#include <hip/hip_runtime.h>
#include <hip/hip_bf16.h>
#include <math.h>

// Problem constants: B,T,D = 8,2048,1024; HID=1024, OUT=512, H=4, WIN=9
#define B_    8
#define T_    2048
#define D_    1024
#define HID_  1024
#define H_    4
#define DK_   256     // HID_/H_
#define S_ELEMS ((size_t)16384 * 1024)   // M * HID

typedef __bf16 bf16x8  __attribute__((ext_vector_type(8)));
typedef __bf16 bf16x4v __attribute__((ext_vector_type(4)));
typedef float  f32x4   __attribute__((ext_vector_type(4)));

__device__ __forceinline__ float gelu_f(float x) {
    return 0.5f * x * (1.0f + erff(x * 0.70710678118654752440f));
}

__device__ __forceinline__ void gload_lds16(const void* g, void* s) {
    __builtin_amdgcn_global_load_lds(
        (const __attribute__((address_space(1))) void*)g,
        (__attribute__((address_space(3))) void*)s, 16, 0, 0);
}

// ---------------------------------------------------------------------------
// 256x256 bf16 GEMM (round-6 min-barrier variant — best measured, VGPR 104).
// BK=64, 8 waves (2Mx4N), 512 threads, T2 LDS swizzle (verified 0 conflicts).
// stage(t+1) 8 loads -> vmcnt(8) [tile t resident, t+1 in flight] -> barrier
// -> 2x{24 ds_read_b128, setprio(1) 32 MFMA setprio(0)} -> barrier.
// EPI 0: QKV fused - Cb+sel*S_ELEMS gets bf16(acc+bias[col]); sel = col>>10
// EPI 1: Cb[m,n] = bf16(acc + bias[n] + res[m,n])   (O-proj + residual, bf16)
// ---------------------------------------------------------------------------
template<int EPI>
__global__ __launch_bounds__(512) void gemm256_k(
    const __bf16* __restrict__ A, const __bf16* __restrict__ Bt,
    const float* __restrict__ bias, const float* __restrict__ res,
    float* __restrict__ Cf, __bf16* __restrict__ Cb,
    int M, int N, int K)
{
    __shared__ __bf16 lds[2][2][256 * 64];
    const int tid = threadIdx.x;
    const int w  = tid >> 6, l = tid & 63;
    const int wm = w >> 2,  wn = w & 3;
    const int lr = l & 15, lq = l >> 4, lx = l & 7;
    const int m0 = blockIdx.x * 256, n0 = blockIdx.y * 256;
    const int nt = K >> 6;

    f32x4 acc[8][4] = {};

    int srow[4], sslot[4];
    #pragma unroll
    for (int c = 0; c < 4; ++c) {
        int i = tid + c * 512;
        srow[c]  = i >> 3;
        sslot[c] = (i & 7) ^ (srow[c] & 7);
    }
    const int ldsu = (w * 64) * 16;

    auto stageA = [&](int t) {
        char* dst = (char*)&lds[t & 1][0][0];
        #pragma unroll
        for (int c = 0; c < 4; ++c)
            gload_lds16((const char*)(A + (size_t)(m0 + srow[c]) * K + t * 64) + (sslot[c] << 4),
                        dst + ldsu + c * 512 * 16);
    };
    auto stageB = [&](int t) {
        char* dst = (char*)&lds[t & 1][1][0];
        #pragma unroll
        for (int c = 0; c < 4; ++c)
            gload_lds16((const char*)(Bt + (size_t)(n0 + srow[c]) * K + t * 64) + (sslot[c] << 4),
                        dst + ldsu + c * 512 * 16);
    };

    stageA(0);
    stageB(0);

    for (int t = 0; t < nt; ++t) {
        const int cur = t & 1;
        if (t + 1 < nt) {
            stageA(t + 1);
            stageB(t + 1);
            asm volatile("s_waitcnt vmcnt(8)" ::: "memory");
        } else {
            asm volatile("s_waitcnt vmcnt(0)" ::: "memory");
        }
        __builtin_amdgcn_s_barrier();        // tile t visible to all waves
        asm volatile("" ::: "memory");

        const char* Ap = (const char*)&lds[cur][0][0];
        const char* Bp = (const char*)&lds[cur][1][0];

        #pragma unroll
        for (int ks = 0; ks < 2; ++ks) {
            bf16x8 af[8], bfr[4];
            #pragma unroll
            for (int fi = 0; fi < 8; ++fi)
                af[fi] = *(const bf16x8*)(Ap + (wm * 128 + fi * 16 + lr) * 128
                                             + ((((ks << 2) | lq) ^ lx) << 4));
            #pragma unroll
            for (int fj = 0; fj < 4; ++fj)
                bfr[fj] = *(const bf16x8*)(Bp + (wn * 64 + fj * 16 + lr) * 128
                                              + ((((ks << 2) | lq) ^ lx) << 4));
            __builtin_amdgcn_s_setprio(1);
            #pragma unroll
            for (int fi = 0; fi < 8; ++fi)
                #pragma unroll
                for (int fj = 0; fj < 4; ++fj)
                    acc[fi][fj] = __builtin_amdgcn_mfma_f32_16x16x32_bf16(
                        af[fi], bfr[fj], acc[fi][fj], 0, 0, 0);
            __builtin_amdgcn_s_setprio(0);
        }
        __builtin_amdgcn_s_barrier();        // all reads of buf[cur] done
        asm volatile("" ::: "memory");
    }

    #pragma unroll
    for (int fi = 0; fi < 8; ++fi) {
        const int row0 = m0 + wm * 128 + fi * 16 + lq * 4;
        #pragma unroll
        for (int fj = 0; fj < 4; ++fj) {
            const int col = n0 + wn * 64 + fj * 16 + lr;
            const float bz = bias[col];
            if (EPI == 0) {
                const int sel = col >> 10, cl = col & 1023;
                __bf16* out = Cb + (size_t)sel * S_ELEMS + (size_t)row0 * 1024 + cl;
                #pragma unroll
                for (int r = 0; r < 4; ++r)
                    out[(size_t)r * 1024] = (__bf16)(acc[fi][fj][r] + bz);
            } else {
                #pragma unroll
                for (int r = 0; r < 4; ++r) {
                    size_t idx = (size_t)(row0 + r) * N + col;
                    Cb[idx] = (__bf16)(acc[fi][fj][r] + bz + res[idx]);
                }
            }
        }
    }
}

// ---------------------------------------------------------------------------
// 256x128 bf16 GEMM for the FFNs (same pipeline class as gemm256: BK=64,
// 8 waves 2Mx4N -> per-wave 128x32 out, acc[8][2]; LDS 96 KiB (A 32K + B 16K,
// double-buffered); same T2 swizzle both-sides; 6 loads/tile -> vmcnt(6)).
// N=512 -> grid (64,4) = 256 blocks = 1/CU exactly.
// EPI 2: Cf[b,n,t] = gelu(acc+bias)  AND  Cb[m,n] = bf16(gelu)  (FFN1)
// EPI 3: Cf[b,n,t] = gelu(acc+bias)                             (FFN2)
// ---------------------------------------------------------------------------
template<int EPI>
__global__ __launch_bounds__(512) void gemmF_k(
    const __bf16* __restrict__ A, const __bf16* __restrict__ Bt,
    const float* __restrict__ bias,
    float* __restrict__ Cf, __bf16* __restrict__ Cb,
    int M, int N, int K)
{
    __shared__ __bf16 lds[2][384 * 64];      // A: [0,256*64) ; B: [256*64,384*64)
    const int tid = threadIdx.x;
    const int w  = tid >> 6, l = tid & 63;
    const int wm = w >> 2,  wn = w & 3;
    const int lr = l & 15, lq = l >> 4, lx = l & 7;
    const int m0 = blockIdx.x * 256, n0 = blockIdx.y * 128;
    const int nt = K >> 6;

    f32x4 acc[8][2] = {};

    int srA[4], ssA[4], srB[2], ssB[2];
    #pragma unroll
    for (int c = 0; c < 4; ++c) {
        int i = tid + c * 512;
        srA[c] = i >> 3;
        ssA[c] = (i & 7) ^ (srA[c] & 7);
    }
    #pragma unroll
    for (int c = 0; c < 2; ++c) {
        int i = tid + c * 512;
        srB[c] = i >> 3;                      // 0..127
        ssB[c] = (i & 7) ^ (srB[c] & 7);
    }
    const int ldsu = (w * 64) * 16;

    auto stage = [&](int t) {
        char* dst = (char*)&lds[t & 1][0];
        #pragma unroll
        for (int c = 0; c < 4; ++c)
            gload_lds16((const char*)(A + (size_t)(m0 + srA[c]) * K + t * 64) + (ssA[c] << 4),
                        dst + ldsu + c * 512 * 16);
        char* dstB = dst + 256 * 64 * 2;      // 32768 B
        #pragma unroll
        for (int c = 0; c < 2; ++c)
            gload_lds16((const char*)(Bt + (size_t)(n0 + srB[c]) * K + t * 64) + (ssB[c] << 4),
                        dstB + ldsu + c * 512 * 16);
    };

    stage(0);

    for (int t = 0; t < nt; ++t) {
        const int cur = t & 1;
        if (t + 1 < nt) {
            stage(t + 1);
            asm volatile("s_waitcnt vmcnt(6)" ::: "memory");
        } else {
            asm volatile("s_waitcnt vmcnt(0)" ::: "memory");
        }
        __builtin_amdgcn_s_barrier();
        asm volatile("" ::: "memory");

        const char* Ap = (const char*)&lds[cur][0];
        const char* Bp = Ap + 256 * 64 * 2;

        #pragma unroll
        for (int ks = 0; ks < 2; ++ks) {
            bf16x8 af[8], bfr[2];
            #pragma unroll
            for (int fi = 0; fi < 8; ++fi)
                af[fi] = *(const bf16x8*)(Ap + (wm * 128 + fi * 16 + lr) * 128
                                             + ((((ks << 2) | lq) ^ lx) << 4));
            #pragma unroll
            for (int fj = 0; fj < 2; ++fj)
                bfr[fj] = *(const bf16x8*)(Bp + (wn * 32 + fj * 16 + lr) * 128
                                              + ((((ks << 2) | lq) ^ lx) << 4));
            __builtin_amdgcn_s_setprio(1);
            #pragma unroll
            for (int fi = 0; fi < 8; ++fi)
                #pragma unroll
                for (int fj = 0; fj < 2; ++fj)
                    acc[fi][fj] = __builtin_amdgcn_mfma_f32_16x16x32_bf16(
                        af[fi], bfr[fj], acc[fi][fj], 0, 0, 0);
            __builtin_amdgcn_s_setprio(0);
        }
        __builtin_amdgcn_s_barrier();
        asm volatile("" ::: "memory");
    }

    #pragma unroll
    for (int fi = 0; fi < 8; ++fi) {
        const int row0 = m0 + wm * 128 + fi * 16 + lq * 4;
        #pragma unroll
        for (int fj = 0; fj < 2; ++fj) {
            const int col = n0 + wn * 32 + fj * 16 + lr;
            const float bz = bias[col];
            float gv[4];
            #pragma unroll
            for (int r = 0; r < 4; ++r) gv[r] = gelu_f(acc[fi][fj][r] + bz);
            const int bidx = row0 >> 11, t0 = row0 & (T_ - 1);
            float4 g4; g4.x = gv[0]; g4.y = gv[1]; g4.z = gv[2]; g4.w = gv[3];
            *(float4*)(Cf + (size_t)bidx * N * T_ + (size_t)col * T_ + t0) = g4;
            if (EPI == 2) {
                #pragma unroll
                for (int r = 0; r < 4; ++r)
                    Cb[(size_t)(row0 + r) * N + col] = (__bf16)gv[r];
            }
        }
    }
}

// ---------------------------------------------------------------------------
// Windowed attention v3 (round-5 proven): 8 threads/query, 32-dim slices,
// no LDS, no barriers; 8-lane shfl reduce; per-lane softmax.
// ---------------------------------------------------------------------------
__global__ __launch_bounds__(256) void attn3_k(
    const __bf16* Q, const __bf16* __restrict__ Kg, const __bf16* __restrict__ Vg,
    __bf16* O, const float* __restrict__ aw_p, const float* __restrict__ ab_p)
{
    const int tid = threadIdx.x;
    const int g  = tid & 7;
    const int ql = tid >> 3;
    const int b  = blockIdx.x >> 8;
    const int h  = (blockIdx.x >> 6) & 3;
    const int t  = ((blockIdx.x & 63) << 5) + ql;

    const size_t hbase = (size_t)b * T_ * HID_ + h * DK_ + g * 32;

    const __bf16* qp = Q + hbase + (size_t)t * HID_;
    float qf[32];
    #pragma unroll
    for (int c = 0; c < 4; ++c) {
        bf16x8 v = *(const bf16x8*)(qp + c * 8);
        #pragma unroll
        for (int e = 0; e < 8; ++e) qf[c * 8 + e] = (float)v[e];
    }

    float part[9];
    #pragma unroll
    for (int jj = 0; jj < 9; ++jj) {
        int j  = t - 4 + jj;
        int jc = min(max(j, 0), T_ - 1);
        const __bf16* kp = Kg + hbase + (size_t)jc * HID_;
        float s = 0.f;
        #pragma unroll
        for (int c = 0; c < 4; ++c) {
            bf16x8 kv = *(const bf16x8*)(kp + c * 8);
            #pragma unroll
            for (int e = 0; e < 8; ++e) s = fmaf(qf[c * 8 + e], (float)kv[e], s);
        }
        part[jj] = s;
    }

    #pragma unroll
    for (int jj = 0; jj < 9; ++jj) {
        float v = part[jj];
        v += __shfl_xor(v, 1);
        v += __shfl_xor(v, 2);
        v += __shfl_xor(v, 4);
        part[jj] = v;
    }

    const float aw = *aw_p, ab = *ab_p;
    float sc[9], mx = -1e30f;
    #pragma unroll
    for (int jj = 0; jj < 9; ++jj) {
        int j = t - 4 + jj;
        float d = (float)(jj - 4);
        float adj = __expf(-fabsf(aw * d * d - ab));
        sc[jj] = (j >= 0 && j < T_) ? part[jj] * (1.0f / 16.0f) + adj : -1e30f;
        mx = fmaxf(mx, sc[jj]);
    }
    float wgt[9], sum = 0.f;
    #pragma unroll
    for (int jj = 0; jj < 9; ++jj) { wgt[jj] = __expf(sc[jj] - mx); sum += wgt[jj]; }
    const float inv = 1.0f / sum;

    float o[32];
    #pragma unroll
    for (int e = 0; e < 32; ++e) o[e] = 0.f;
    #pragma unroll
    for (int jj = 0; jj < 9; ++jj) {
        int jc = min(max(t - 4 + jj, 0), T_ - 1);
        const float wj = wgt[jj] * inv;
        const __bf16* vp = Vg + hbase + (size_t)jc * HID_;
        #pragma unroll
        for (int c = 0; c < 4; ++c) {
            bf16x8 vv = *(const bf16x8*)(vp + c * 8);
            #pragma unroll
            for (int e = 0; e < 8; ++e)
                o[c * 8 + e] = fmaf(wj, (float)vv[e], o[c * 8 + e]);
        }
    }

    __bf16* op = O + hbase + (size_t)t * HID_;
    #pragma unroll
    for (int c = 0; c < 4; ++c) {
        bf16x8 ov;
        #pragma unroll
        for (int e = 0; e < 8; ++e) ov[e] = (__bf16)o[c * 8 + e];
        *(bf16x8*)(op + c * 8) = ov;
    }
}

// ---------------------------------------------------------------------------
// LayerNorm over D=1024: bf16 in-place. One 256-thread block per row.
// ---------------------------------------------------------------------------
__device__ __forceinline__ float block_sum(float v, float* sm) {
    #pragma unroll
    for (int off = 32; off; off >>= 1) v += __shfl_xor(v, off);
    if ((threadIdx.x & 63) == 0) sm[threadIdx.x >> 6] = v;
    __syncthreads();
    float r = sm[0] + sm[1] + sm[2] + sm[3];
    __syncthreads();
    return r;
}

__global__ __launch_bounds__(256) void ln_k(
    __bf16* __restrict__ Yb, const float* __restrict__ g, const float* __restrict__ bta)
{
    __shared__ float sm[4];
    __bf16* y = Yb + (size_t)blockIdx.x * D_;
    bf16x4v v4 = *(const bf16x4v*)(y + threadIdx.x * 4);
    float v[4] = { (float)v4[0], (float)v4[1], (float)v4[2], (float)v4[3] };
    float mean = block_sum(v[0] + v[1] + v[2] + v[3], sm) * (1.0f / D_);
    float s2 = 0.f;
    #pragma unroll
    for (int i = 0; i < 4; ++i) { float d = v[i] - mean; s2 += d * d; }
    float rstd = rsqrtf(block_sum(s2, sm) * (1.0f / D_) + 1e-5f);
    bf16x4v o;
    #pragma unroll
    for (int i = 0; i < 4; ++i) {
        int idx = threadIdx.x * 4 + i;
        o[i] = (__bf16)((v[i] - mean) * rstd * g[idx] + bta[idx]);
    }
    *(bf16x4v*)(y + threadIdx.x * 4) = o;
}

// ---------------------------------------------------------------------------
// Fused prep: cast x (16384 blocks), W1 (512), W2 (256), pack biases (12).
// ---------------------------------------------------------------------------
__global__ __launch_bounds__(256) void prep_k(
    const float4* __restrict__ x4, const float4* __restrict__ W14,
    const float4* __restrict__ W24,
    const float* __restrict__ bq, const float* __restrict__ bk,
    const float* __restrict__ bv,
    bf16x4v* __restrict__ xb4, bf16x4v* __restrict__ W1b4,
    bf16x4v* __restrict__ W2b4, float* __restrict__ bqkvd)
{
    const int bid = blockIdx.x, tid = threadIdx.x;
    if (bid < 16384) {
        int i = bid * 256 + tid;
        float4 v = x4[i];
        bf16x4v o; o[0] = (__bf16)v.x; o[1] = (__bf16)v.y; o[2] = (__bf16)v.z; o[3] = (__bf16)v.w;
        xb4[i] = o;
    } else if (bid < 16896) {
        int i = (bid - 16384) * 256 + tid;
        float4 v = W14[i];
        bf16x4v o; o[0] = (__bf16)v.x; o[1] = (__bf16)v.y; o[2] = (__bf16)v.z; o[3] = (__bf16)v.w;
        W1b4[i] = o;
    } else if (bid < 17152) {
        int i = (bid - 16896) * 256 + tid;
        float4 v = W24[i];
        bf16x4v o; o[0] = (__bf16)v.x; o[1] = (__bf16)v.y; o[2] = (__bf16)v.z; o[3] = (__bf16)v.w;
        W2b4[i] = o;
    } else {
        int i = (bid - 17152) * 256 + tid;   // 0..3071
        bqkvd[i] = (i < 1024) ? bq[i] : ((i < 2048) ? bk[i - 1024] : bv[i - 2048]);
    }
}

// castT of the four 1024x1024 weights in one launch (blockIdx.z selects).
__global__ void castT4_k(const float* __restrict__ Wq, const float* __restrict__ Wk,
                         const float* __restrict__ Wv, const float* __restrict__ Wo,
                         __bf16* __restrict__ Wqkv, __bf16* __restrict__ Wot)
{
    __shared__ float tbuf[32][33];
    const int z = blockIdx.z;
    const float* in = (z == 0) ? Wq : (z == 1) ? Wk : (z == 2) ? Wv : Wo;
    __bf16* out = (z < 3) ? (Wqkv + (size_t)z * 1024 * 1024) : Wot;
    int k0 = blockIdx.x * 32, n0 = blockIdx.y * 32;
    for (int r = threadIdx.y; r < 32; r += 8)
        tbuf[r][threadIdx.x] = in[(size_t)(k0 + r) * 1024 + n0 + threadIdx.x];
    __syncthreads();
    for (int r = threadIdx.y; r < 32; r += 8)
        out[(size_t)(n0 + r) * 1024 + k0 + threadIdx.x] = (__bf16)tbuf[threadIdx.x][r];
}

// ---------------------------------------------------------------------------
extern "C" void kernel_launch(void* const* d_in, const int* in_sizes, int n_in,
                              void* d_out, int out_size, void* d_ws, size_t ws_size,
                              hipStream_t stream) {
    const float* x    = (const float*)d_in[0];
    const float* Wq   = (const float*)d_in[2];
    const float* bq   = (const float*)d_in[3];
    const float* Wk   = (const float*)d_in[4];
    const float* bk   = (const float*)d_in[5];
    const float* Wv   = (const float*)d_in[6];
    const float* bv   = (const float*)d_in[7];
    const float* Wo   = (const float*)d_in[8];
    const float* bo   = (const float*)d_in[9];
    const float* ln_g = (const float*)d_in[10];
    const float* ln_b = (const float*)d_in[11];
    const float* W1   = (const float*)d_in[12];  // [512,1024] already [N,K]
    const float* b1   = (const float*)d_in[13];
    const float* W2   = (const float*)d_in[14];  // [512,512]  already [N,K]
    const float* b2   = (const float*)d_in[15];
    const float* adj_w = (const float*)d_in[16];
    const float* adj_b = (const float*)d_in[17];

    const int M = B_ * T_;                  // 16384
    const size_t S = S_ELEMS;               // 16.78M elems

    __bf16* Qb   = (__bf16*)d_ws;           // S  (also attention output O)
    __bf16* Kb   = Qb + S;                  // S  (dead after attn -> Yb bf16)
    __bf16* Vb   = Kb + S;                  // S
    __bf16* Yb   = Kb;                      // alias: post-residual bf16 y
    __bf16* xb   = Vb + S;                  // S
    __bf16* Wqkv = xb + S;                  // 3*1M  ([3072,1024] bf16, N-major)
    __bf16* Wot  = Wqkv + 3 * 1024 * 1024;  // 1M
    __bf16* W1b  = Wot + 1024 * 1024;       // 512*1024
    __bf16* W2b  = W1b + 512 * 1024;        // 512*512
    __bf16* h1b  = W2b + 512 * 512;         // M*512
    float*  bqkvd = (float*)(h1b + (size_t)M * 512);  // 3072 f32

    float* xe = (float*)d_out;                         // [B,512,T]
    float* h1 = xe + (size_t)B_ * 512 * T_;            // [B,512,T]

    dim3 blk(256);

    // --- prep: casts + bias pack (2 launches) ---
    prep_k<<<dim3(17164), blk, 0, stream>>>(
        (const float4*)x, (const float4*)W1, (const float4*)W2, bq, bk, bv,
        (bf16x4v*)xb, (bf16x4v*)W1b, (bf16x4v*)W2b, bqkvd);
    castT4_k<<<dim3(32, 32, 4), dim3(32, 8), 0, stream>>>(Wq, Wk, Wv, Wo, Wqkv, Wot);

    // --- QKV fused projection (256^2 pipelined MFMA): N=3072 ---
    gemm256_k<0><<<dim3(M / 256, 3072 / 256), dim3(512), 0, stream>>>(
        xb, Wqkv, bqkvd, nullptr, nullptr, Qb, M, 3072, D_);

    // --- windowed attention v3 (O overwrites Qb) ---
    attn3_k<<<dim3(B_ * H_ * (T_ / 32)), blk, 0, stream>>>(Qb, Kb, Vb, Qb, adj_w, adj_b);

    // --- O-projection + bias + residual -> Yb bf16 ---
    gemm256_k<1><<<dim3(M / 256, HID_ / 256), dim3(512), 0, stream>>>(
        Qb, Wot, bo, x, nullptr, Yb, M, D_, HID_);

    // --- LayerNorm in place (bf16) ---
    ln_k<<<dim3(M), blk, 0, stream>>>(Yb, ln_g, ln_b);

    // --- FFN1 (256x128 pipeline): gelu(W1 @ y^T) -> f32 h1 + bf16 h1b ---
    gemmF_k<2><<<dim3(M / 256, 512 / 128), dim3(512), 0, stream>>>(
        Yb, W1b, b1, h1, h1b, M, 512, D_);

    // --- FFN2 (256x128 pipeline): gelu(W2 @ h1) -> f32 xe ---
    gemmF_k<3><<<dim3(M / 256, 512 / 128), dim3(512), 0, stream>>>(
        h1b, W2b, b2, xe, nullptr, M, 512, 512);
}

// Round 11
// 296.454 us; speedup vs baseline: 1.1350x; 1.0766x over previous
//
#include <hip/hip_runtime.h>
#include <hip/hip_bf16.h>
#include <math.h>

// Problem constants: B,T,D = 8,2048,1024; HID=1024, OUT=512, H=4, WIN=9
#define B_    8
#define T_    2048
#define D_    1024
#define HID_  1024
#define H_    4
#define DK_   256     // HID_/H_
#define S_ELEMS ((size_t)16384 * 1024)   // M * HID

typedef __bf16 bf16x8  __attribute__((ext_vector_type(8)));
typedef __bf16 bf16x4v __attribute__((ext_vector_type(4)));
typedef float  f32x4   __attribute__((ext_vector_type(4)));

__device__ __forceinline__ float gelu_f(float x) {
    return 0.5f * x * (1.0f + erff(x * 0.70710678118654752440f));
}

__device__ __forceinline__ void gload_lds16(const void* g, void* s) {
    __builtin_amdgcn_global_load_lds(
        (const __attribute__((address_space(1))) void*)g,
        (__attribute__((address_space(3))) void*)s, 16, 0, 0);
}

// ---------------------------------------------------------------------------
// 256x256 bf16 GEMM (round-6 min-barrier variant — best measured, VGPR 104).
// BK=64, 8 waves (2Mx4N), 512 threads, T2 LDS swizzle (verified 0 conflicts).
// stage(t+1) 8 loads -> vmcnt(8) -> barrier -> 2x{24 ds_read_b128,
// setprio(1) 32 MFMA setprio(0)} -> barrier.  [~888 TF plateau: 5 schedule
// variants within ±3% — documented structure ceiling; do not re-tweak.]
// EPI 0: QKV fused - Cb+sel*S_ELEMS gets bf16(acc+bias[col]); sel = col>>10
// EPI 1: Cb[m,n] = bf16(acc + bias[n] + res[m,n])   (O-proj + residual, bf16)
// ---------------------------------------------------------------------------
template<int EPI>
__global__ __launch_bounds__(512) void gemm256_k(
    const __bf16* __restrict__ A, const __bf16* __restrict__ Bt,
    const float* __restrict__ bias, const float* __restrict__ res,
    float* __restrict__ Cf, __bf16* __restrict__ Cb,
    int M, int N, int K)
{
    __shared__ __bf16 lds[2][2][256 * 64];
    const int tid = threadIdx.x;
    const int w  = tid >> 6, l = tid & 63;
    const int wm = w >> 2,  wn = w & 3;
    const int lr = l & 15, lq = l >> 4, lx = l & 7;
    const int m0 = blockIdx.x * 256, n0 = blockIdx.y * 256;
    const int nt = K >> 6;

    f32x4 acc[8][4] = {};

    int srow[4], sslot[4];
    #pragma unroll
    for (int c = 0; c < 4; ++c) {
        int i = tid + c * 512;
        srow[c]  = i >> 3;
        sslot[c] = (i & 7) ^ (srow[c] & 7);
    }
    const int ldsu = (w * 64) * 16;

    auto stageA = [&](int t) {
        char* dst = (char*)&lds[t & 1][0][0];
        #pragma unroll
        for (int c = 0; c < 4; ++c)
            gload_lds16((const char*)(A + (size_t)(m0 + srow[c]) * K + t * 64) + (sslot[c] << 4),
                        dst + ldsu + c * 512 * 16);
    };
    auto stageB = [&](int t) {
        char* dst = (char*)&lds[t & 1][1][0];
        #pragma unroll
        for (int c = 0; c < 4; ++c)
            gload_lds16((const char*)(Bt + (size_t)(n0 + srow[c]) * K + t * 64) + (sslot[c] << 4),
                        dst + ldsu + c * 512 * 16);
    };

    stageA(0);
    stageB(0);

    for (int t = 0; t < nt; ++t) {
        const int cur = t & 1;
        if (t + 1 < nt) {
            stageA(t + 1);
            stageB(t + 1);
            asm volatile("s_waitcnt vmcnt(8)" ::: "memory");
        } else {
            asm volatile("s_waitcnt vmcnt(0)" ::: "memory");
        }
        __builtin_amdgcn_s_barrier();        // tile t visible to all waves
        asm volatile("" ::: "memory");

        const char* Ap = (const char*)&lds[cur][0][0];
        const char* Bp = (const char*)&lds[cur][1][0];

        #pragma unroll
        for (int ks = 0; ks < 2; ++ks) {
            bf16x8 af[8], bfr[4];
            #pragma unroll
            for (int fi = 0; fi < 8; ++fi)
                af[fi] = *(const bf16x8*)(Ap + (wm * 128 + fi * 16 + lr) * 128
                                             + ((((ks << 2) | lq) ^ lx) << 4));
            #pragma unroll
            for (int fj = 0; fj < 4; ++fj)
                bfr[fj] = *(const bf16x8*)(Bp + (wn * 64 + fj * 16 + lr) * 128
                                              + ((((ks << 2) | lq) ^ lx) << 4));
            __builtin_amdgcn_s_setprio(1);
            #pragma unroll
            for (int fi = 0; fi < 8; ++fi)
                #pragma unroll
                for (int fj = 0; fj < 4; ++fj)
                    acc[fi][fj] = __builtin_amdgcn_mfma_f32_16x16x32_bf16(
                        af[fi], bfr[fj], acc[fi][fj], 0, 0, 0);
            __builtin_amdgcn_s_setprio(0);
        }
        __builtin_amdgcn_s_barrier();        // all reads of buf[cur] done
        asm volatile("" ::: "memory");
    }

    #pragma unroll
    for (int fi = 0; fi < 8; ++fi) {
        const int row0 = m0 + wm * 128 + fi * 16 + lq * 4;
        #pragma unroll
        for (int fj = 0; fj < 4; ++fj) {
            const int col = n0 + wn * 64 + fj * 16 + lr;
            const float bz = bias[col];
            if (EPI == 0) {
                const int sel = col >> 10, cl = col & 1023;
                __bf16* out = Cb + (size_t)sel * S_ELEMS + (size_t)row0 * 1024 + cl;
                #pragma unroll
                for (int r = 0; r < 4; ++r)
                    out[(size_t)r * 1024] = (__bf16)(acc[fi][fj][r] + bz);
            } else {
                #pragma unroll
                for (int r = 0; r < 4; ++r) {
                    size_t idx = (size_t)(row0 + r) * N + col;
                    Cb[idx] = (__bf16)(acc[fi][fj][r] + bz + res[idx]);
                }
            }
        }
    }
}

// ---------------------------------------------------------------------------
// 256x128 bf16 GEMM for the FFNs (round-10 proven). BK=64, 8 waves 2Mx4N,
// acc[8][2]; LDS 96 KiB dbuf; same T2 swizzle; 6 loads/tile -> vmcnt(6).
// EPI 2: Cf[b,n,t] = gelu(acc+bias)  AND  Cb[m,n] = bf16(gelu)  (FFN1)
// EPI 3: Cf[b,n,t] = gelu(acc+bias)                             (FFN2)
// ---------------------------------------------------------------------------
template<int EPI>
__global__ __launch_bounds__(512) void gemmF_k(
    const __bf16* __restrict__ A, const __bf16* __restrict__ Bt,
    const float* __restrict__ bias,
    float* __restrict__ Cf, __bf16* __restrict__ Cb,
    int M, int N, int K)
{
    __shared__ __bf16 lds[2][384 * 64];      // A: [0,256*64) ; B: [256*64,384*64)
    const int tid = threadIdx.x;
    const int w  = tid >> 6, l = tid & 63;
    const int wm = w >> 2,  wn = w & 3;
    const int lr = l & 15, lq = l >> 4, lx = l & 7;
    const int m0 = blockIdx.x * 256, n0 = blockIdx.y * 128;
    const int nt = K >> 6;

    f32x4 acc[8][2] = {};

    int srA[4], ssA[4], srB[2], ssB[2];
    #pragma unroll
    for (int c = 0; c < 4; ++c) {
        int i = tid + c * 512;
        srA[c] = i >> 3;
        ssA[c] = (i & 7) ^ (srA[c] & 7);
    }
    #pragma unroll
    for (int c = 0; c < 2; ++c) {
        int i = tid + c * 512;
        srB[c] = i >> 3;
        ssB[c] = (i & 7) ^ (srB[c] & 7);
    }
    const int ldsu = (w * 64) * 16;

    auto stage = [&](int t) {
        char* dst = (char*)&lds[t & 1][0];
        #pragma unroll
        for (int c = 0; c < 4; ++c)
            gload_lds16((const char*)(A + (size_t)(m0 + srA[c]) * K + t * 64) + (ssA[c] << 4),
                        dst + ldsu + c * 512 * 16);
        char* dstB = dst + 256 * 64 * 2;
        #pragma unroll
        for (int c = 0; c < 2; ++c)
            gload_lds16((const char*)(Bt + (size_t)(n0 + srB[c]) * K + t * 64) + (ssB[c] << 4),
                        dstB + ldsu + c * 512 * 16);
    };

    stage(0);

    for (int t = 0; t < nt; ++t) {
        const int cur = t & 1;
        if (t + 1 < nt) {
            stage(t + 1);
            asm volatile("s_waitcnt vmcnt(6)" ::: "memory");
        } else {
            asm volatile("s_waitcnt vmcnt(0)" ::: "memory");
        }
        __builtin_amdgcn_s_barrier();
        asm volatile("" ::: "memory");

        const char* Ap = (const char*)&lds[cur][0];
        const char* Bp = Ap + 256 * 64 * 2;

        #pragma unroll
        for (int ks = 0; ks < 2; ++ks) {
            bf16x8 af[8], bfr[2];
            #pragma unroll
            for (int fi = 0; fi < 8; ++fi)
                af[fi] = *(const bf16x8*)(Ap + (wm * 128 + fi * 16 + lr) * 128
                                             + ((((ks << 2) | lq) ^ lx) << 4));
            #pragma unroll
            for (int fj = 0; fj < 2; ++fj)
                bfr[fj] = *(const bf16x8*)(Bp + (wn * 32 + fj * 16 + lr) * 128
                                              + ((((ks << 2) | lq) ^ lx) << 4));
            __builtin_amdgcn_s_setprio(1);
            #pragma unroll
            for (int fi = 0; fi < 8; ++fi)
                #pragma unroll
                for (int fj = 0; fj < 2; ++fj)
                    acc[fi][fj] = __builtin_amdgcn_mfma_f32_16x16x32_bf16(
                        af[fi], bfr[fj], acc[fi][fj], 0, 0, 0);
            __builtin_amdgcn_s_setprio(0);
        }
        __builtin_amdgcn_s_barrier();
        asm volatile("" ::: "memory");
    }

    #pragma unroll
    for (int fi = 0; fi < 8; ++fi) {
        const int row0 = m0 + wm * 128 + fi * 16 + lq * 4;
        #pragma unroll
        for (int fj = 0; fj < 2; ++fj) {
            const int col = n0 + wn * 32 + fj * 16 + lr;
            const float bz = bias[col];
            float gv[4];
            #pragma unroll
            for (int r = 0; r < 4; ++r) gv[r] = gelu_f(acc[fi][fj][r] + bz);
            const int bidx = row0 >> 11, t0 = row0 & (T_ - 1);
            float4 g4; g4.x = gv[0]; g4.y = gv[1]; g4.z = gv[2]; g4.w = gv[3];
            *(float4*)(Cf + (size_t)bidx * N * T_ + (size_t)col * T_ + t0) = g4;
            if (EPI == 2) {
                #pragma unroll
                for (int r = 0; r < 4; ++r)
                    Cb[(size_t)(row0 + r) * N + col] = (__bf16)gv[r];
            }
        }
    }
}

// ---------------------------------------------------------------------------
// Windowed attention v4: 16 threads per query, 16-dim slices.
// Rationale (round-10 diagnosis): attn3 (8 thr/query, 32-dim slices) was
// latency/MLP-bound (~110 VGPR -> ~4 waves/SIMD, 76 dependent 16B loads).
// Halving the slice gives ~80 VGPR -> ~6 waves/SIMD -> ~1.5-2x loads in
// flight, same total VALU. Reduce over masks 1,2,4,8 (intra-wave).
// No LDS, no barriers. O may alias Q (thread reads only its own q slice
// before writing the same slice).
// ---------------------------------------------------------------------------
__global__ __launch_bounds__(256) void attn4_k(
    const __bf16* Q, const __bf16* __restrict__ Kg, const __bf16* __restrict__ Vg,
    __bf16* O, const float* __restrict__ aw_p, const float* __restrict__ ab_p)
{
    const int tid = threadIdx.x;
    const int s  = tid & 15;              // dim slice [s*16, s*16+16)
    const int ql = tid >> 4;              // query within block (0..15)
    const int b  = blockIdx.x >> 9;
    const int h  = (blockIdx.x >> 7) & 3;
    const int t  = ((blockIdx.x & 127) << 4) + ql;

    const size_t hbase = (size_t)b * T_ * HID_ + h * DK_ + s * 16;

    const __bf16* qp = Q + hbase + (size_t)t * HID_;
    float qf[16];
    #pragma unroll
    for (int c = 0; c < 2; ++c) {
        bf16x8 v = *(const bf16x8*)(qp + c * 8);
        #pragma unroll
        for (int e = 0; e < 8; ++e) qf[c * 8 + e] = (float)v[e];
    }

    // partial dots, 9 slots, uniform trip count (clamped addresses)
    float part[9];
    #pragma unroll
    for (int jj = 0; jj < 9; ++jj) {
        int jc = min(max(t - 4 + jj, 0), T_ - 1);
        const __bf16* kp = Kg + hbase + (size_t)jc * HID_;
        float sacc = 0.f;
        #pragma unroll
        for (int c = 0; c < 2; ++c) {
            bf16x8 kv = *(const bf16x8*)(kp + c * 8);
            #pragma unroll
            for (int e = 0; e < 8; ++e) sacc = fmaf(qf[c * 8 + e], (float)kv[e], sacc);
        }
        part[jj] = sacc;
    }

    // reduce across the 16 lanes of this query (masks 1,2,4,8 stay in-group)
    #pragma unroll
    for (int jj = 0; jj < 9; ++jj) {
        float v = part[jj];
        v += __shfl_xor(v, 1);
        v += __shfl_xor(v, 2);
        v += __shfl_xor(v, 4);
        v += __shfl_xor(v, 8);
        part[jj] = v;
    }

    const float aw = *aw_p, ab = *ab_p;
    float sc[9], mx = -1e30f;
    #pragma unroll
    for (int jj = 0; jj < 9; ++jj) {
        int j = t - 4 + jj;
        float d = (float)(jj - 4);
        float adj = __expf(-fabsf(aw * d * d - ab));
        sc[jj] = (j >= 0 && j < T_) ? part[jj] * (1.0f / 16.0f) + adj : -1e30f;
        mx = fmaxf(mx, sc[jj]);
    }
    float wgt[9], sum = 0.f;
    #pragma unroll
    for (int jj = 0; jj < 9; ++jj) { wgt[jj] = __expf(sc[jj] - mx); sum += wgt[jj]; }
    const float inv = 1.0f / sum;

    float o[16];
    #pragma unroll
    for (int e = 0; e < 16; ++e) o[e] = 0.f;
    #pragma unroll
    for (int jj = 0; jj < 9; ++jj) {
        int jc = min(max(t - 4 + jj, 0), T_ - 1);
        const float wj = wgt[jj] * inv;
        const __bf16* vp = Vg + hbase + (size_t)jc * HID_;
        #pragma unroll
        for (int c = 0; c < 2; ++c) {
            bf16x8 vv = *(const bf16x8*)(vp + c * 8);
            #pragma unroll
            for (int e = 0; e < 8; ++e)
                o[c * 8 + e] = fmaf(wj, (float)vv[e], o[c * 8 + e]);
        }
    }

    __bf16* op = O + hbase + (size_t)t * HID_;
    #pragma unroll
    for (int c = 0; c < 2; ++c) {
        bf16x8 ov;
        #pragma unroll
        for (int e = 0; e < 8; ++e) ov[e] = (__bf16)o[c * 8 + e];
        *(bf16x8*)(op + c * 8) = ov;
    }
}

// ---------------------------------------------------------------------------
// LayerNorm over D=1024: bf16 in-place. One 256-thread block per row.
// ---------------------------------------------------------------------------
__device__ __forceinline__ float block_sum(float v, float* sm) {
    #pragma unroll
    for (int off = 32; off; off >>= 1) v += __shfl_xor(v, off);
    if ((threadIdx.x & 63) == 0) sm[threadIdx.x >> 6] = v;
    __syncthreads();
    float r = sm[0] + sm[1] + sm[2] + sm[3];
    __syncthreads();
    return r;
}

__global__ __launch_bounds__(256) void ln_k(
    __bf16* __restrict__ Yb, const float* __restrict__ g, const float* __restrict__ bta)
{
    __shared__ float sm[4];
    __bf16* y = Yb + (size_t)blockIdx.x * D_;
    bf16x4v v4 = *(const bf16x4v*)(y + threadIdx.x * 4);
    float v[4] = { (float)v4[0], (float)v4[1], (float)v4[2], (float)v4[3] };
    float mean = block_sum(v[0] + v[1] + v[2] + v[3], sm) * (1.0f / D_);
    float s2 = 0.f;
    #pragma unroll
    for (int i = 0; i < 4; ++i) { float d = v[i] - mean; s2 += d * d; }
    float rstd = rsqrtf(block_sum(s2, sm) * (1.0f / D_) + 1e-5f);
    bf16x4v o;
    #pragma unroll
    for (int i = 0; i < 4; ++i) {
        int idx = threadIdx.x * 4 + i;
        o[i] = (__bf16)((v[i] - mean) * rstd * g[idx] + bta[idx]);
    }
    *(bf16x4v*)(y + threadIdx.x * 4) = o;
}

// ---------------------------------------------------------------------------
// Fused prep (one launch): cast x (16384 blocks), W1 (512), W2 (256),
// pack biases (12), and the four 1024x1024 weight transposes (4096 blocks,
// 32x32 tiles via LDS). All threads of a block take the same branch, so the
// __syncthreads in the transpose branch is safe.
// ---------------------------------------------------------------------------
__global__ __launch_bounds__(256) void prep_k(
    const float4* __restrict__ x4, const float4* __restrict__ W14,
    const float4* __restrict__ W24,
    const float* __restrict__ bq, const float* __restrict__ bk,
    const float* __restrict__ bv,
    const float* __restrict__ Wq, const float* __restrict__ Wk,
    const float* __restrict__ Wv, const float* __restrict__ Wo,
    bf16x4v* __restrict__ xb4, bf16x4v* __restrict__ W1b4,
    bf16x4v* __restrict__ W2b4, float* __restrict__ bqkvd,
    __bf16* __restrict__ Wqkv, __bf16* __restrict__ Wot)
{
    __shared__ float tbuf[32][33];
    const int bid = blockIdx.x, tid = threadIdx.x;
    if (bid < 16384) {
        int i = bid * 256 + tid;
        float4 v = x4[i];
        bf16x4v o; o[0] = (__bf16)v.x; o[1] = (__bf16)v.y; o[2] = (__bf16)v.z; o[3] = (__bf16)v.w;
        xb4[i] = o;
    } else if (bid < 16896) {
        int i = (bid - 16384) * 256 + tid;
        float4 v = W14[i];
        bf16x4v o; o[0] = (__bf16)v.x; o[1] = (__bf16)v.y; o[2] = (__bf16)v.z; o[3] = (__bf16)v.w;
        W1b4[i] = o;
    } else if (bid < 17152) {
        int i = (bid - 16896) * 256 + tid;
        float4 v = W24[i];
        bf16x4v o; o[0] = (__bf16)v.x; o[1] = (__bf16)v.y; o[2] = (__bf16)v.z; o[3] = (__bf16)v.w;
        W2b4[i] = o;
    } else if (bid < 17164) {
        int i = (bid - 17152) * 256 + tid;   // 0..3071
        bqkvd[i] = (i < 1024) ? bq[i] : ((i < 2048) ? bk[i - 1024] : bv[i - 2048]);
    } else {
        int r  = bid - 17164;                // 0..4095
        int z  = r >> 10;
        int rt = r & 1023;
        int k0 = ((rt >> 5) & 31) << 5, n0 = (rt & 31) << 5;
        const float* in = (z == 0) ? Wq : (z == 1) ? Wk : (z == 2) ? Wv : Wo;
        __bf16* out = (z < 3) ? (Wqkv + (size_t)z * 1024 * 1024) : Wot;
        int xx = tid & 31, yy = tid >> 5;    // 32 x 8
        for (int r2 = yy; r2 < 32; r2 += 8)
            tbuf[r2][xx] = in[(size_t)(k0 + r2) * 1024 + n0 + xx];
        __syncthreads();
        for (int r2 = yy; r2 < 32; r2 += 8)
            out[(size_t)(n0 + r2) * 1024 + k0 + xx] = (__bf16)tbuf[xx][r2];
    }
}

// ---------------------------------------------------------------------------
extern "C" void kernel_launch(void* const* d_in, const int* in_sizes, int n_in,
                              void* d_out, int out_size, void* d_ws, size_t ws_size,
                              hipStream_t stream) {
    const float* x    = (const float*)d_in[0];
    const float* Wq   = (const float*)d_in[2];
    const float* bq   = (const float*)d_in[3];
    const float* Wk   = (const float*)d_in[4];
    const float* bk   = (const float*)d_in[5];
    const float* Wv   = (const float*)d_in[6];
    const float* bv   = (const float*)d_in[7];
    const float* Wo   = (const float*)d_in[8];
    const float* bo   = (const float*)d_in[9];
    const float* ln_g = (const float*)d_in[10];
    const float* ln_b = (const float*)d_in[11];
    const float* W1   = (const float*)d_in[12];  // [512,1024] already [N,K]
    const float* b1   = (const float*)d_in[13];
    const float* W2   = (const float*)d_in[14];  // [512,512]  already [N,K]
    const float* b2   = (const float*)d_in[15];
    const float* adj_w = (const float*)d_in[16];
    const float* adj_b = (const float*)d_in[17];

    const int M = B_ * T_;                  // 16384
    const size_t S = S_ELEMS;               // 16.78M elems

    __bf16* Qb   = (__bf16*)d_ws;           // S  (also attention output O)
    __bf16* Kb   = Qb + S;                  // S  (dead after attn -> Yb bf16)
    __bf16* Vb   = Kb + S;                  // S
    __bf16* Yb   = Kb;                      // alias: post-residual bf16 y
    __bf16* xb   = Vb + S;                  // S
    __bf16* Wqkv = xb + S;                  // 3*1M  ([3072,1024] bf16, N-major)
    __bf16* Wot  = Wqkv + 3 * 1024 * 1024;  // 1M
    __bf16* W1b  = Wot + 1024 * 1024;       // 512*1024
    __bf16* W2b  = W1b + 512 * 1024;        // 512*512
    __bf16* h1b  = W2b + 512 * 512;         // M*512
    float*  bqkvd = (float*)(h1b + (size_t)M * 512);  // 3072 f32

    float* xe = (float*)d_out;                         // [B,512,T]
    float* h1 = xe + (size_t)B_ * 512 * T_;            // [B,512,T]

    dim3 blk(256);

    // --- prep: all casts + transposes + bias pack in ONE launch ---
    prep_k<<<dim3(17164 + 4096), blk, 0, stream>>>(
        (const float4*)x, (const float4*)W1, (const float4*)W2, bq, bk, bv,
        Wq, Wk, Wv, Wo,
        (bf16x4v*)xb, (bf16x4v*)W1b, (bf16x4v*)W2b, bqkvd, Wqkv, Wot);

    // --- QKV fused projection (256^2 pipelined MFMA): N=3072 ---
    gemm256_k<0><<<dim3(M / 256, 3072 / 256), dim3(512), 0, stream>>>(
        xb, Wqkv, bqkvd, nullptr, nullptr, Qb, M, 3072, D_);

    // --- windowed attention v4 (O overwrites Qb): 16 thr/query ---
    attn4_k<<<dim3(B_ * H_ * (T_ / 16)), blk, 0, stream>>>(Qb, Kb, Vb, Qb, adj_w, adj_b);

    // --- O-projection + bias + residual -> Yb bf16 ---
    gemm256_k<1><<<dim3(M / 256, HID_ / 256), dim3(512), 0, stream>>>(
        Qb, Wot, bo, x, nullptr, Yb, M, D_, HID_);

    // --- LayerNorm in place (bf16) ---
    ln_k<<<dim3(M), blk, 0, stream>>>(Yb, ln_g, ln_b);

    // --- FFN1 (256x128 pipeline): gelu(W1 @ y^T) -> f32 h1 + bf16 h1b ---
    gemmF_k<2><<<dim3(M / 256, 512 / 128), dim3(512), 0, stream>>>(
        Yb, W1b, b1, h1, h1b, M, 512, D_);

    // --- FFN2 (256x128 pipeline): gelu(W2 @ h1) -> f32 xe ---
    gemmF_k<3><<<dim3(M / 256, 512 / 128), dim3(512), 0, stream>>>(
        h1b, W2b, b2, xe, nullptr, M, 512, 512);
}